// Round 8
// baseline (2305.430 us; speedup 1.0000x reference)
//
#include <hip/hip_runtime.h>
#include <hip/hip_bf16.h>

// UCCAEncoder: 3x EdgeConv(max) + FFN + gather. R8:
//  - edge kernel rewritten BARRIER-FREE: A (relu(U[dst]+V[src])) and B (W2^T)
//    fragments loaded directly global->registers (no LDS, no global_load_lds,
//    no __syncthreads in the K-loop). Fully unrolled K (immediate offsets),
//    depth-1 register prefetch: iter k's 12 loads fly across iter k-1's 16 MFMAs.
//    Plain register loads are never drained by barriers (the R6 failure mode).
//  - tile 128e x 128n, acc[4][4] (64 AGPR) -> ~3 waves/SIMD.
//  - XCD swizzle: 4 n-tiles of an edge-group 8 blocks apart (same XCD) -> U/V
//    gathers stay L2-local (R7 measured FETCH 442->121 MB).
//  - keeps: sorted edges, fused U/V node GEMM, fp16 z path, run-compressed
//    atomicMax segment-max, decode re-zeroes keys, MFMA FFN.

#define N_NODES 16384
#define EDGES   262144
#define HDIM    512
#define SEQ     2048

typedef __attribute__((ext_vector_type(8))) short short8;
typedef __attribute__((ext_vector_type(8))) _Float16 half8;
typedef __attribute__((ext_vector_type(4))) float f32x4;

__device__ __forceinline__ void gld16(const void* g, void* l) {
    __builtin_amdgcn_global_load_lds(
        (const __attribute__((address_space(1))) void*)g,
        (__attribute__((address_space(3))) void*)l, 16, 0, 0);
}
__device__ __forceinline__ unsigned short f2b(float f) {   // fp32 -> bf16 RNE
    unsigned int x = __float_as_uint(f);
    return (unsigned short)((x + 0x7fffu + ((x >> 16) & 1u)) >> 16);
}
__device__ __forceinline__ unsigned short f2h(float f) {   // fp32 -> fp16 bits
    _Float16 h = (_Float16)f;
    return __builtin_bit_cast(unsigned short, h);
}
// LDS k-seg swizzle: physical slot = logical_seg ^ ((row>>1)&3)
__device__ __forceinline__ short8 frag_ld(const short* S, int row, int q) {
    int p = q ^ ((row >> 1) & 3);
    return *(const short8*)(S + row * 32 + p * 8);
}
// stage 128 rows x 32 k (16-bit elems) via global_load_lds, swizzled slots
__device__ __forceinline__ void stage_tile(const short* G, int kc, short* S, int t) {
#pragma unroll
    for (int it = 0; it < 2; ++it) {
        int lin = it * 256 + t;
        int row = lin >> 2, p = lin & 3;
        int q = p ^ ((row >> 1) & 3);
        gld16(G + (size_t)row * HDIM + kc + q * 8, S + lin * 8);
    }
}
__device__ __forceinline__ void mfma_tile_bf16(const short* As, const short* Bs,
                                               int wm, int wn, int l, f32x4 acc[4][4]) {
    short8 a[4], b[4];
#pragma unroll
    for (int mt = 0; mt < 4; ++mt) a[mt] = frag_ld(As, wm + mt * 16 + (l & 15), l >> 4);
#pragma unroll
    for (int nt = 0; nt < 4; ++nt) b[nt] = frag_ld(Bs, wn + nt * 16 + (l & 15), l >> 4);
#pragma unroll
    for (int mt = 0; mt < 4; ++mt)
#pragma unroll
        for (int nt = 0; nt < 4; ++nt)
            acc[mt][nt] = __builtin_amdgcn_mfma_f32_16x16x32_bf16(a[mt], b[nt], acc[mt][nt], 0, 0, 0);
}

// ================= edge sort (counting sort by dst) =================
__global__ __launch_bounds__(256) void hist_kernel(
    const int* __restrict__ dst, int* __restrict__ hist) {
    int idx = blockIdx.x * 256 + threadIdx.x;
    atomicAdd(&hist[dst[idx]], 1);
}
__global__ __launch_bounds__(256) void scan_kernel(
    const int* __restrict__ hist, int* __restrict__ cursor) {
    __shared__ int part[256];
    const int t = threadIdx.x, base = t * 64;
    int sum = 0;
    for (int i = 0; i < 64; ++i) sum += hist[base + i];
    part[t] = sum;
    __syncthreads();
    int run = 0;
    for (int i = 0; i < t; ++i) run += part[i];
    for (int i = 0; i < 64; ++i) {
        int h = hist[base + i];
        cursor[base + i] = run;
        run += h;
    }
}
__global__ __launch_bounds__(256) void scatter_kernel(
    const int* __restrict__ dst, const int* __restrict__ src,
    int* __restrict__ cursor, int* __restrict__ dstS, int* __restrict__ srcS) {
    int idx = blockIdx.x * 256 + threadIdx.x;
    int d = dst[idx];
    int p = atomicAdd(&cursor[d], 1);
    dstS[p] = d;
    srcS[p] = src[idx];
}

// ================= weights / input prep =================
// conv trio -> [n][k]: z=0 Wd=w1a-w1b (bf16), z=1 w1b (bf16), z=2 w2 (fp16)
__global__ __launch_bounds__(256) void prep_weights_kernel(
    const float* __restrict__ w1, const float* __restrict__ w2,
    short* __restrict__ WdT, short* __restrict__ w1bT, short* __restrict__ W2T) {
    __shared__ float tile[32][33];
    const int which = blockIdx.z;
    const int k0 = blockIdx.x * 32, n0 = blockIdx.y * 32;
    const int tx = threadIdx.x, ty = threadIdx.y;
#pragma unroll
    for (int i = 0; i < 4; ++i) {
        int k = k0 + ty + i * 8, n = n0 + tx;
        float v;
        if (which == 0)      v = w1[k * 512 + n] - w1[(k + 512) * 512 + n];
        else if (which == 1) v = w1[(k + 512) * 512 + n];
        else                 v = w2[k * 512 + n];
        tile[ty + i * 8][tx] = v;
    }
    __syncthreads();
    short* out = which == 0 ? WdT : (which == 1 ? w1bT : W2T);
#pragma unroll
    for (int i = 0; i < 4; ++i) {
        int n = n0 + ty + i * 8, k = k0 + tx;
        float v = tile[tx][ty + i * 8];
        out[(size_t)n * 512 + k] = (short)(which == 2 ? f2h(v) : f2b(v));
    }
}
// FFN mats (bf16): z=0 fw1, z=1 fw2
__global__ __launch_bounds__(256) void tr_kernel(
    const float* __restrict__ W1, const float* __restrict__ W2,
    short* __restrict__ T1, short* __restrict__ T2) {
    __shared__ float tile[32][33];
    const float* W = blockIdx.z ? W2 : W1;
    short* T = blockIdx.z ? T2 : T1;
    const int k0 = blockIdx.x * 32, n0 = blockIdx.y * 32;
    const int tx = threadIdx.x, ty = threadIdx.y;
#pragma unroll
    for (int i = 0; i < 4; ++i)
        tile[ty + i * 8][tx] = W[(k0 + ty + i * 8) * 512 + n0 + tx];
    __syncthreads();
#pragma unroll
    for (int i = 0; i < 4; ++i)
        T[(size_t)(n0 + ty + i * 8) * 512 + k0 + tx] = (short)f2b(tile[tx][ty + i * 8]);
}
__global__ __launch_bounds__(256) void cvt_bf16_kernel(
    const float* __restrict__ x, short* __restrict__ xb) {
    int idx = blockIdx.x * 256 + threadIdx.x;
    float4 v = ((const float4*)x)[idx];
    uint2 o;
    o.x = (unsigned int)f2b(v.x) | ((unsigned int)f2b(v.y) << 16);
    o.y = (unsigned int)f2b(v.z) | ((unsigned int)f2b(v.w) << 16);
    ((uint2*)xb)[idx] = o;
}

// ================= fused U/V node GEMM (bf16 in, fp16 out) =================
// grid (128, 8): y<4 -> U = h@WdT^T + b1 ; y>=4 -> V = h@w1bT^T
__global__ __launch_bounds__(256) void node_gemm_uv_kernel(
    const short* __restrict__ A, const short* __restrict__ WdT,
    const short* __restrict__ w1bT, const float* __restrict__ b1,
    short* __restrict__ U, short* __restrict__ V) {
    __shared__ short As[128 * 32];
    __shared__ short Bs[128 * 32];
    const int t = threadIdx.x;
    const int by = blockIdx.y;
    const short* Wt = (by < 4) ? WdT : w1bT;
    short* C = (by < 4) ? U : V;
    const float* bias = (by < 4) ? b1 : nullptr;
    const int m0 = blockIdx.x * 128, n0 = (by & 3) * 128;
    const int w = t >> 6, l = t & 63;
    const int wm = (w & 1) * 64, wn = (w >> 1) * 64;
    f32x4 acc[4][4] = {};
    for (int kc = 0; kc < HDIM; kc += 32) {
        stage_tile(A + (size_t)m0 * HDIM, kc, As, t);
        stage_tile(Wt + (size_t)n0 * HDIM, kc, Bs, t);
        __syncthreads();
        mfma_tile_bf16(As, Bs, wm, wn, l, acc);
        __syncthreads();
    }
#pragma unroll
    for (int mt = 0; mt < 4; ++mt) {
        int m = m0 + wm + mt * 16 + (l >> 4) * 4;
#pragma unroll
        for (int nt = 0; nt < 4; ++nt) {
            int n = n0 + wn + nt * 16 + (l & 15);
            float bv = bias ? bias[n] : 0.f;
#pragma unroll
            for (int r = 0; r < 4; ++r)
                C[(size_t)(m + r) * HDIM + n] = (short)f2h(acc[mt][nt][r] + bv);
        }
    }
}

// ====== edge GEMM (sorted, fp16, 128e x 128n, register-direct, NO barriers) ======
__device__ __forceinline__ void kflush(unsigned int* K, int d, int col, float m) {
    unsigned int b = __float_as_uint(m);
    unsigned int key = ((int)b < 0) ? ~b : (b | 0x80000000u);
    atomicMax(K + (((size_t)d) << 9) + col, key);
}
__global__ __launch_bounds__(256) void edge_mfma_kernel(
    const short* __restrict__ U, const short* __restrict__ V,
    const short* __restrict__ Wt, const int* __restrict__ srcS,
    const int* __restrict__ dstS, unsigned int* __restrict__ K) {
    __shared__ int sdst[128], ssrc[128];
    const int t = threadIdx.x;
    // XCD swizzle: L%8 = XCD; the 4 n-tiles of edge-group g are 8 apart (same XCD).
    const int L   = blockIdx.x;                // 0..8191
    const int g   = (L >> 5) * 8 + (L & 7);    // edge-group 0..2047
    const int nt4 = (L >> 3) & 3;              // n-tile 0..3
    const int e0 = g * 128, n0 = nt4 * 128;
    if (t < 128) { sdst[t] = dstS[e0 + t]; ssrc[t] = srcS[e0 + t]; }
    __syncthreads();                           // only barrier in the kernel
    const int w = t >> 6, l = t & 63;
    const int wm = (w & 1) * 64, wn = (w >> 1) * 64;
    const int lm = l & 15, lk = (l >> 4) * 8;
    // 32-bit element offsets from uniform bases (saddr + voffset form)
    int ou[4], ov[4], ob[4];
#pragma unroll
    for (int mt = 0; mt < 4; ++mt) {
        int r = wm + mt * 16 + lm;
        ou[mt] = (sdst[r] << 9) + lk;
        ov[mt] = (ssrc[r] << 9) + lk;
        ob[mt] = ((n0 + wn + mt * 16 + lm) << 9) + lk;
    }
    f32x4 acc[4][4] = {};
    half8 u[4], v[4], b[4];
#pragma unroll
    for (int mt = 0; mt < 4; ++mt) {
        u[mt] = *(const half8*)(U + ou[mt]);
        v[mt] = *(const half8*)(V + ov[mt]);
        b[mt] = *(const half8*)(Wt + ob[mt]);
    }
#pragma unroll
    for (int kc8 = 0; kc8 < 16; ++kc8) {
        half8 a[4], bb[4];
#pragma unroll
        for (int mt = 0; mt < 4; ++mt) {
            half8 s = u[mt] + v[mt];           // v_pk_add_f16
            half8 z = {};
            a[mt]  = __builtin_elementwise_max(s, z);   // v_pk_max_f16 (relu)
            bb[mt] = b[mt];
        }
        if (kc8 < 15) {                        // prefetch next k-chunk (in flight across MFMAs)
            const int o = (kc8 + 1) * 32;
#pragma unroll
            for (int mt = 0; mt < 4; ++mt) {
                u[mt] = *(const half8*)(U + ou[mt] + o);
                v[mt] = *(const half8*)(V + ov[mt] + o);
                b[mt] = *(const half8*)(Wt + ob[mt] + o);
            }
        }
#pragma unroll
        for (int mt = 0; mt < 4; ++mt)
#pragma unroll
            for (int nt = 0; nt < 4; ++nt)
                acc[mt][nt] = __builtin_amdgcn_mfma_f32_16x16x32_f16(a[mt], bb[nt], acc[mt][nt], 0, 0, 0);
    }
    // epilogue: run-compressed segment-max (sorted dst -> few flushes)
#pragma unroll
    for (int mt = 0; mt < 4; ++mt) {
        int base = wm + mt * 16 + (l >> 4) * 4;
        int d0 = sdst[base], d1 = sdst[base + 1], d2 = sdst[base + 2], d3 = sdst[base + 3];
#pragma unroll
        for (int nt = 0; nt < 4; ++nt) {
            int col = n0 + wn + nt * 16 + lm;
            f32x4 a = acc[mt][nt];
            float m = a[0];
            if (d1 == d0) m = fmaxf(m, a[1]); else { kflush(K, d0, col, m); m = a[1]; }
            if (d2 == d1) m = fmaxf(m, a[2]); else { kflush(K, d1, col, m); m = a[2]; }
            if (d3 == d2) m = fmaxf(m, a[3]); else { kflush(K, d2, col, m); m = a[3]; }
            kflush(K, d3, col, m);
        }
    }
}

// ================= decode keys -> h bf16; re-zero keys for next layer =================
__global__ __launch_bounds__(256) void decode_kernel(
    unsigned int* __restrict__ K, const float* __restrict__ b2,
    short* __restrict__ hb) {
    int idx = blockIdx.x * 256 + threadIdx.x;
    unsigned int k = K[idx];
    K[idx] = 0u;                       // init for next layer's atomicMax
    int c = idx & (HDIM - 1);
    float v = 0.f;
    if (k != 0u) {
        unsigned int b = (k & 0x80000000u) ? (k ^ 0x80000000u) : ~k;
        v = __uint_as_float(b) + b2[c];
    }
    hb[idx] = (short)f2b(fmaxf(v, 0.f));
}

// ================= gather (bf16) =================
__global__ __launch_bounds__(256) void gather_bf16_kernel(
    const short* __restrict__ hb, const int* __restrict__ sel,
    short* __restrict__ hgb) {
    int idx = blockIdx.x * 256 + threadIdx.x;          // 4096 rows x 64 chunks
    int row = idx >> 6, c = idx & 63;
    int b = row >> 9;                                  // SEL = 512
    int s = sel[row];
    ((uint4*)hgb)[idx] = ((const uint4*)(hb + (((size_t)(b * SEQ + s)) << 9)))[c];
}

// ================= MFMA GEMM (FFN), bf16 in, bf16 or fp32 out =================
__global__ __launch_bounds__(256) void ffn_gemm_kernel(
    const short* __restrict__ A, const short* __restrict__ Wt,
    const float* __restrict__ bias, short* __restrict__ Cb,
    float* __restrict__ Cf, int relu) {
    __shared__ short As[128 * 32];
    __shared__ short Bs[128 * 32];
    const int t = threadIdx.x;
    const int m0 = blockIdx.x * 128, n0 = blockIdx.y * 128;
    const int w = t >> 6, l = t & 63;
    const int wm = (w & 1) * 64, wn = (w >> 1) * 64;
    f32x4 acc[4][4] = {};
    for (int kc = 0; kc < HDIM; kc += 32) {
        stage_tile(A + (size_t)m0 * HDIM, kc, As, t);
        stage_tile(Wt + (size_t)n0 * HDIM, kc, Bs, t);
        __syncthreads();
        mfma_tile_bf16(As, Bs, wm, wn, l, acc);
        __syncthreads();
    }
#pragma unroll
    for (int mt = 0; mt < 4; ++mt) {
        int m = m0 + wm + mt * 16 + (l >> 4) * 4;
#pragma unroll
        for (int nt = 0; nt < 4; ++nt) {
            int n = n0 + wn + nt * 16 + (l & 15);
            float bv = bias[n];
#pragma unroll
            for (int r = 0; r < 4; ++r) {
                float v = acc[mt][nt][r] + bv;
                if (relu) v = fmaxf(v, 0.f);
                if (Cf) Cf[(size_t)(m + r) * HDIM + n] = v;
                else    Cb[(size_t)(m + r) * HDIM + n] = (short)f2b(v);
            }
        }
    }
}

extern "C" void kernel_launch(void* const* d_in, const int* in_sizes, int n_in,
                              void* d_out, int out_size, void* d_ws, size_t ws_size,
                              hipStream_t stream) {
    const float* x   = (const float*)d_in[0];
    const int*   ei  = (const int*)d_in[1];
    const int*   sel = (const int*)d_in[2];
    const int*   src = ei;
    const int*   dst = ei + EDGES;
    const float* cw1[3] = {(const float*)d_in[4],  (const float*)d_in[8],  (const float*)d_in[12]};
    const float* cb1[3] = {(const float*)d_in[5],  (const float*)d_in[9],  (const float*)d_in[13]};
    const float* cw2[3] = {(const float*)d_in[6],  (const float*)d_in[10], (const float*)d_in[14]};
    const float* cb2[3] = {(const float*)d_in[7],  (const float*)d_in[11], (const float*)d_in[15]};
    const float* fw1 = (const float*)d_in[16];
    const float* fb1 = (const float*)d_in[17];
    const float* fw2 = (const float*)d_in[18];
    const float* fb2 = (const float*)d_in[19];
    float* out = (float*)d_out;

    const size_t MB = 1024 * 1024;
    char* p = (char*)d_ws;
    unsigned int* keys = (unsigned int*)p;                   // 32 MB
    short* U    = (short*)(p + 32 * MB);                     // 16 MB (fp16)
    short* V    = (short*)(p + 48 * MB);                     // 16 MB (fp16)
    short* hb   = (short*)(p + 64 * MB);                     // 16 MB (bf16)
    short* WdT  = (short*)(p + 80 * MB);                     // 0.5 MB each
    short* w1bT = WdT + 512 * 512;
    short* W2T  = w1bT + 512 * 512;                          // fp16
    short* fw1T = W2T + 512 * 512;
    short* fw2T = fw1T + 512 * 512;
    int*   dstS = (int*)(p + 83 * MB);                       // 1 MB
    int*   srcS = (int*)(p + 84 * MB);                       // 1 MB
    int*   hist = (int*)(p + 85 * MB);                       // 64 KB
    int*   curs = hist + N_NODES;                            // 64 KB
    short* hgb  = (short*)(p + 86 * MB);                     // 4 MB
    short* t1b  = (short*)(p + 90 * MB);                     // 4 MB

    // --- sort edges by dst (edges constant across layers) ---
    (void)hipMemsetAsync(hist, 0, N_NODES * sizeof(int), stream);
    hist_kernel<<<EDGES / 256, 256, 0, stream>>>(dst, hist);
    scan_kernel<<<1, 256, 0, stream>>>(hist, curs);
    scatter_kernel<<<EDGES / 256, 256, 0, stream>>>(dst, src, curs, dstS, srcS);

    cvt_bf16_kernel<<<8192, 256, 0, stream>>>(x, hb);
    tr_kernel<<<dim3(16, 16, 2), dim3(32, 8), 0, stream>>>(fw1, fw2, fw1T, fw2T);
    (void)hipMemsetAsync(keys, 0, 32 * MB, stream);          // layer-0 key init

    for (int l = 0; l < 3; ++l) {
        prep_weights_kernel<<<dim3(16, 16, 3), dim3(32, 8), 0, stream>>>(
            cw1[l], cw2[l], WdT, w1bT, W2T);
        node_gemm_uv_kernel<<<dim3(128, 8), 256, 0, stream>>>(hb, WdT, w1bT, cb1[l], U, V);
        edge_mfma_kernel<<<8192, 256, 0, stream>>>(U, V, W2T, srcS, dstS, keys);
        decode_kernel<<<(N_NODES * HDIM) / 256, 256, 0, stream>>>(keys, cb2[l], hb);
    }

    gather_bf16_kernel<<<(4096 * 64) / 256, 256, 0, stream>>>(hb, sel, hgb);
    ffn_gemm_kernel<<<dim3(32, 4), 256, 0, stream>>>(hgb, fw1T, fb1, t1b, nullptr, 1);
    ffn_gemm_kernel<<<dim3(32, 4), 256, 0, stream>>>(t1b, fw2T, fb2, nullptr, out, 0);
}

// Round 9
// 1322.290 us; speedup vs baseline: 1.7435x; 1.7435x over previous
//
#include <hip/hip_runtime.h>
#include <hip/hip_bf16.h>

// UCCAEncoder: 3x EdgeConv(max) + FFN + gather. R9:
//  - edge kernel = R7 structure (best so far) with Bk=64: each U/V row gather is
//    one aligned 128B line per iter (halves scattered L2 transactions), and only
//    8 barrier pairs instead of 16.
//  - LDS row stride 128B = exact bank wrap -> swizzle p = seg ^ ((row>>1)&7) ^ (row&1)
//    on BOTH ds_write/DMA staging and ds_read frags (2-way aliasing = free).
//  - keeps: sorted edges, XCD swizzle, fused U/V node GEMM, fp16 z path,
//    run-compressed atomicMax segment-max, decode re-zeroes keys, MFMA FFN.

#define N_NODES 16384
#define EDGES   262144
#define HDIM    512
#define SEQ     2048

typedef __attribute__((ext_vector_type(8))) short short8;
typedef __attribute__((ext_vector_type(8))) _Float16 half8;
typedef __attribute__((ext_vector_type(2))) _Float16 half2v;
typedef __attribute__((ext_vector_type(4))) float f32x4;

__device__ __forceinline__ void gld16(const void* g, void* l) {
    __builtin_amdgcn_global_load_lds(
        (const __attribute__((address_space(1))) void*)g,
        (__attribute__((address_space(3))) void*)l, 16, 0, 0);
}
__device__ __forceinline__ unsigned short f2b(float f) {   // fp32 -> bf16 RNE
    unsigned int x = __float_as_uint(f);
    return (unsigned short)((x + 0x7fffu + ((x >> 16) & 1u)) >> 16);
}
__device__ __forceinline__ unsigned short f2h(float f) {   // fp32 -> fp16 bits
    _Float16 h = (_Float16)f;
    return __builtin_bit_cast(unsigned short, h);
}
// packed fp16: z = max(u+v, 0) (v_pk_add_f16 + v_pk_max_f16)
__device__ __forceinline__ unsigned int zpack_h(unsigned int u, unsigned int v) {
    half2v a = __builtin_bit_cast(half2v, u);
    half2v b = __builtin_bit_cast(half2v, v);
    half2v s = a + b;
    half2v z = {(_Float16)0.f, (_Float16)0.f};
    half2v r = __builtin_elementwise_max(s, z);
    return __builtin_bit_cast(unsigned int, r);
}
// ---- Bk=32 LDS swizzle (node/FFN GEMMs): slot = seg ^ ((row>>1)&3), row stride 64B
__device__ __forceinline__ short8 frag_ld(const short* S, int row, int q) {
    int p = q ^ ((row >> 1) & 3);
    return *(const short8*)(S + row * 32 + p * 8);
}
__device__ __forceinline__ void stage_tile(const short* G, int kc, short* S, int t) {
#pragma unroll
    for (int it = 0; it < 2; ++it) {
        int lin = it * 256 + t;
        int row = lin >> 2, p = lin & 3;
        int q = p ^ ((row >> 1) & 3);
        gld16(G + (size_t)row * HDIM + kc + q * 8, S + lin * 8);
    }
}
__device__ __forceinline__ void mfma_tile_bf16(const short* As, const short* Bs,
                                               int wm, int wn, int l, f32x4 acc[4][4]) {
    short8 a[4], b[4];
#pragma unroll
    for (int mt = 0; mt < 4; ++mt) a[mt] = frag_ld(As, wm + mt * 16 + (l & 15), l >> 4);
#pragma unroll
    for (int nt = 0; nt < 4; ++nt) b[nt] = frag_ld(Bs, wn + nt * 16 + (l & 15), l >> 4);
#pragma unroll
    for (int mt = 0; mt < 4; ++mt)
#pragma unroll
        for (int nt = 0; nt < 4; ++nt)
            acc[mt][nt] = __builtin_amdgcn_mfma_f32_16x16x32_bf16(a[mt], b[nt], acc[mt][nt], 0, 0, 0);
}
// ---- Bk=64 LDS swizzle (edge kernel): row stride 128B = bank wrap ->
//      slot = seg ^ ((row>>1)&7) ^ (row&1); 8 segs of 8 els per row.
__device__ __forceinline__ half8 frag64(const short* S, int row, int q) {
    int p = q ^ ((row >> 1) & 7) ^ (row & 1);
    return *(const half8*)(S + row * 64 + p * 8);
}

// ================= edge sort (counting sort by dst) =================
__global__ __launch_bounds__(256) void hist_kernel(
    const int* __restrict__ dst, int* __restrict__ hist) {
    int idx = blockIdx.x * 256 + threadIdx.x;
    atomicAdd(&hist[dst[idx]], 1);
}
__global__ __launch_bounds__(256) void scan_kernel(
    const int* __restrict__ hist, int* __restrict__ cursor) {
    __shared__ int part[256];
    const int t = threadIdx.x, base = t * 64;
    int sum = 0;
    for (int i = 0; i < 64; ++i) sum += hist[base + i];
    part[t] = sum;
    __syncthreads();
    int run = 0;
    for (int i = 0; i < t; ++i) run += part[i];
    for (int i = 0; i < 64; ++i) {
        int h = hist[base + i];
        cursor[base + i] = run;
        run += h;
    }
}
__global__ __launch_bounds__(256) void scatter_kernel(
    const int* __restrict__ dst, const int* __restrict__ src,
    int* __restrict__ cursor, int* __restrict__ dstS, int* __restrict__ srcS) {
    int idx = blockIdx.x * 256 + threadIdx.x;
    int d = dst[idx];
    int p = atomicAdd(&cursor[d], 1);
    dstS[p] = d;
    srcS[p] = src[idx];
}

// ================= weights / input prep =================
// conv trio -> [n][k]: z=0 Wd=w1a-w1b (bf16), z=1 w1b (bf16), z=2 w2 (fp16)
__global__ __launch_bounds__(256) void prep_weights_kernel(
    const float* __restrict__ w1, const float* __restrict__ w2,
    short* __restrict__ WdT, short* __restrict__ w1bT, short* __restrict__ W2T) {
    __shared__ float tile[32][33];
    const int which = blockIdx.z;
    const int k0 = blockIdx.x * 32, n0 = blockIdx.y * 32;
    const int tx = threadIdx.x, ty = threadIdx.y;
#pragma unroll
    for (int i = 0; i < 4; ++i) {
        int k = k0 + ty + i * 8, n = n0 + tx;
        float v;
        if (which == 0)      v = w1[k * 512 + n] - w1[(k + 512) * 512 + n];
        else if (which == 1) v = w1[(k + 512) * 512 + n];
        else                 v = w2[k * 512 + n];
        tile[ty + i * 8][tx] = v;
    }
    __syncthreads();
    short* out = which == 0 ? WdT : (which == 1 ? w1bT : W2T);
#pragma unroll
    for (int i = 0; i < 4; ++i) {
        int n = n0 + ty + i * 8, k = k0 + tx;
        float v = tile[tx][ty + i * 8];
        out[(size_t)n * 512 + k] = (short)(which == 2 ? f2h(v) : f2b(v));
    }
}
// FFN mats (bf16): z=0 fw1, z=1 fw2
__global__ __launch_bounds__(256) void tr_kernel(
    const float* __restrict__ W1, const float* __restrict__ W2,
    short* __restrict__ T1, short* __restrict__ T2) {
    __shared__ float tile[32][33];
    const float* W = blockIdx.z ? W2 : W1;
    short* T = blockIdx.z ? T2 : T1;
    const int k0 = blockIdx.x * 32, n0 = blockIdx.y * 32;
    const int tx = threadIdx.x, ty = threadIdx.y;
#pragma unroll
    for (int i = 0; i < 4; ++i)
        tile[ty + i * 8][tx] = W[(k0 + ty + i * 8) * 512 + n0 + tx];
    __syncthreads();
#pragma unroll
    for (int i = 0; i < 4; ++i)
        T[(size_t)(n0 + ty + i * 8) * 512 + k0 + tx] = (short)f2b(tile[tx][ty + i * 8]);
}
__global__ __launch_bounds__(256) void cvt_bf16_kernel(
    const float* __restrict__ x, short* __restrict__ xb) {
    int idx = blockIdx.x * 256 + threadIdx.x;
    float4 v = ((const float4*)x)[idx];
    uint2 o;
    o.x = (unsigned int)f2b(v.x) | ((unsigned int)f2b(v.y) << 16);
    o.y = (unsigned int)f2b(v.z) | ((unsigned int)f2b(v.w) << 16);
    ((uint2*)xb)[idx] = o;
}

// ================= fused U/V node GEMM (bf16 in, fp16 out) =================
// grid (128, 8): y<4 -> U = h@WdT^T + b1 ; y>=4 -> V = h@w1bT^T
__global__ __launch_bounds__(256) void node_gemm_uv_kernel(
    const short* __restrict__ A, const short* __restrict__ WdT,
    const short* __restrict__ w1bT, const float* __restrict__ b1,
    short* __restrict__ U, short* __restrict__ V) {
    __shared__ short As[128 * 32];
    __shared__ short Bs[128 * 32];
    const int t = threadIdx.x;
    const int by = blockIdx.y;
    const short* Wt = (by < 4) ? WdT : w1bT;
    short* C = (by < 4) ? U : V;
    const float* bias = (by < 4) ? b1 : nullptr;
    const int m0 = blockIdx.x * 128, n0 = (by & 3) * 128;
    const int w = t >> 6, l = t & 63;
    const int wm = (w & 1) * 64, wn = (w >> 1) * 64;
    f32x4 acc[4][4] = {};
    for (int kc = 0; kc < HDIM; kc += 32) {
        stage_tile(A + (size_t)m0 * HDIM, kc, As, t);
        stage_tile(Wt + (size_t)n0 * HDIM, kc, Bs, t);
        __syncthreads();
        mfma_tile_bf16(As, Bs, wm, wn, l, acc);
        __syncthreads();
    }
#pragma unroll
    for (int mt = 0; mt < 4; ++mt) {
        int m = m0 + wm + mt * 16 + (l >> 4) * 4;
#pragma unroll
        for (int nt = 0; nt < 4; ++nt) {
            int n = n0 + wn + nt * 16 + (l & 15);
            float bv = bias ? bias[n] : 0.f;
#pragma unroll
            for (int r = 0; r < 4; ++r)
                C[(size_t)(m + r) * HDIM + n] = (short)f2h(acc[mt][nt][r] + bv);
        }
    }
}

// ====== edge GEMM (sorted, fp16, 128e x 256n, Bk=64) + fused segment-max ======
__device__ __forceinline__ void kflush(unsigned int* K, int d, int col, float m) {
    unsigned int b = __float_as_uint(m);
    unsigned int key = ((int)b < 0) ? ~b : (b | 0x80000000u);
    atomicMax(K + (((size_t)d) << 9) + col, key);
}
__global__ __launch_bounds__(256, 2) void edge_mfma_kernel(
    const short* __restrict__ U, const short* __restrict__ V,
    const short* __restrict__ Wt, const int* __restrict__ srcS,
    const int* __restrict__ dstS, unsigned int* __restrict__ K) {
    __shared__ short As[128 * 64];        // 16 KB (z, fp16, Bk=64)
    __shared__ short Bs[256 * 64];        // 32 KB (W2^T, fp16, 2 n-tiles)
    __shared__ int sdst[128], ssrc[128];
    const int t = threadIdx.x;
    // XCD swizzle: L%8 = XCD; the 2 n-halves of edge-group g are 8 apart (same XCD).
    const int L  = blockIdx.x;                 // 0..4095
    const int g  = (L >> 4) * 8 + (L & 7);     // edge-group 0..2047
    const int nh = (L >> 3) & 1;               // n-half
    const int e0 = g * 128, n0 = nh * 256;
    if (t < 128) { sdst[t] = dstS[e0 + t]; ssrc[t] = srcS[e0 + t]; }
    __syncthreads();
    const int w = t >> 6, l = t & 63;
    const int wm = (w & 1) * 64;               // 64-edge half
    const int wnb = (w >> 1) * 128;            // 128-n half within Bs
    const int lm = l & 15;
    const int arow = t >> 1, ahalf = t & 1;    // thread covers 64B half of its row
    const short* up = U + (((size_t)sdst[arow]) << 9) + ahalf * 32;
    const short* vp = V + (((size_t)ssrc[arow]) << 9) + ahalf * 32;
    unsigned int* As_u = (unsigned int*)As;
    f32x4 acc[4][8] = {};

    for (int kc = 0; kc < HDIM; kc += 64) {
        // B tile: 256 rows x 64 els via DMA; logical seg q at physical slot s
#pragma unroll
        for (int it = 0; it < 8; ++it) {
            int lin = it * 256 + t;
            int row = lin >> 3, s = lin & 7;
            int q = s ^ ((row >> 1) & 7) ^ (row & 1);
            gld16(Wt + (size_t)(n0 + row) * HDIM + kc + q * 8, Bs + lin * 8);
        }
        // A tile: each thread packs 64B (4 segs) of its row; all 8 lane-requests
        // per row land in ONE aligned 128B line (kc steps are 128B).
#pragma unroll
        for (int j = 0; j < 4; ++j) {
            uint4 uu = *(const uint4*)(up + kc + j * 8);
            uint4 vv = *(const uint4*)(vp + kc + j * 8);
            uint4 z;
            z.x = zpack_h(uu.x, vv.x); z.y = zpack_h(uu.y, vv.y);
            z.z = zpack_h(uu.z, vv.z); z.w = zpack_h(uu.w, vv.w);
            int seg = ahalf * 4 + j;
            int p = seg ^ ((arow >> 1) & 7) ^ (arow & 1);
            *(uint4*)(As_u + arow * 32 + p * 4) = z;
        }
        __syncthreads();
#pragma unroll
        for (int kh = 0; kh < 2; ++kh) {
            const int q = kh * 4 + (l >> 4);
            half8 b[8];
#pragma unroll
            for (int nt = 0; nt < 8; ++nt)
                b[nt] = frag64(Bs, wnb + nt * 16 + lm, q);
#pragma unroll
            for (int mt = 0; mt < 4; ++mt) {
                half8 a = frag64(As, wm + mt * 16 + lm, q);
#pragma unroll
                for (int nt = 0; nt < 8; ++nt)
                    acc[mt][nt] = __builtin_amdgcn_mfma_f32_16x16x32_f16(a, b[nt], acc[mt][nt], 0, 0, 0);
            }
        }
        __syncthreads();
    }
    // epilogue: run-compressed segment-max (sorted dst -> few flushes)
#pragma unroll
    for (int mt = 0; mt < 4; ++mt) {
        int base = wm + mt * 16 + (l >> 4) * 4;
        int d0 = sdst[base], d1 = sdst[base + 1], d2 = sdst[base + 2], d3 = sdst[base + 3];
#pragma unroll
        for (int nt = 0; nt < 8; ++nt) {
            int col = n0 + wnb + nt * 16 + lm;
            f32x4 a = acc[mt][nt];
            float m = a[0];
            if (d1 == d0) m = fmaxf(m, a[1]); else { kflush(K, d0, col, m); m = a[1]; }
            if (d2 == d1) m = fmaxf(m, a[2]); else { kflush(K, d1, col, m); m = a[2]; }
            if (d3 == d2) m = fmaxf(m, a[3]); else { kflush(K, d2, col, m); m = a[3]; }
            kflush(K, d3, col, m);
        }
    }
}

// ================= decode keys -> h bf16; re-zero keys for next layer =================
__global__ __launch_bounds__(256) void decode_kernel(
    unsigned int* __restrict__ K, const float* __restrict__ b2,
    short* __restrict__ hb) {
    int idx = blockIdx.x * 256 + threadIdx.x;
    unsigned int k = K[idx];
    K[idx] = 0u;                       // init for next layer's atomicMax
    int c = idx & (HDIM - 1);
    float v = 0.f;
    if (k != 0u) {
        unsigned int b = (k & 0x80000000u) ? (k ^ 0x80000000u) : ~k;
        v = __uint_as_float(b) + b2[c];
    }
    hb[idx] = (short)f2b(fmaxf(v, 0.f));
}

// ================= gather (bf16) =================
__global__ __launch_bounds__(256) void gather_bf16_kernel(
    const short* __restrict__ hb, const int* __restrict__ sel,
    short* __restrict__ hgb) {
    int idx = blockIdx.x * 256 + threadIdx.x;          // 4096 rows x 64 chunks
    int row = idx >> 6, c = idx & 63;
    int b = row >> 9;                                  // SEL = 512
    int s = sel[row];
    ((uint4*)hgb)[idx] = ((const uint4*)(hb + (((size_t)(b * SEQ + s)) << 9)))[c];
}

// ================= MFMA GEMM (FFN), bf16 in, bf16 or fp32 out =================
__global__ __launch_bounds__(256) void ffn_gemm_kernel(
    const short* __restrict__ A, const short* __restrict__ Wt,
    const float* __restrict__ bias, short* __restrict__ Cb,
    float* __restrict__ Cf, int relu) {
    __shared__ short As[128 * 32];
    __shared__ short Bs[128 * 32];
    const int t = threadIdx.x;
    const int m0 = blockIdx.x * 128, n0 = blockIdx.y * 128;
    const int w = t >> 6, l = t & 63;
    const int wm = (w & 1) * 64, wn = (w >> 1) * 64;
    f32x4 acc[4][4] = {};
    for (int kc = 0; kc < HDIM; kc += 32) {
        stage_tile(A + (size_t)m0 * HDIM, kc, As, t);
        stage_tile(Wt + (size_t)n0 * HDIM, kc, Bs, t);
        __syncthreads();
        mfma_tile_bf16(As, Bs, wm, wn, l, acc);
        __syncthreads();
    }
#pragma unroll
    for (int mt = 0; mt < 4; ++mt) {
        int m = m0 + wm + mt * 16 + (l >> 4) * 4;
#pragma unroll
        for (int nt = 0; nt < 4; ++nt) {
            int n = n0 + wn + nt * 16 + (l & 15);
            float bv = bias[n];
#pragma unroll
            for (int r = 0; r < 4; ++r) {
                float v = acc[mt][nt][r] + bv;
                if (relu) v = fmaxf(v, 0.f);
                if (Cf) Cf[(size_t)(m + r) * HDIM + n] = v;
                else    Cb[(size_t)(m + r) * HDIM + n] = (short)f2b(v);
            }
        }
    }
}

extern "C" void kernel_launch(void* const* d_in, const int* in_sizes, int n_in,
                              void* d_out, int out_size, void* d_ws, size_t ws_size,
                              hipStream_t stream) {
    const float* x   = (const float*)d_in[0];
    const int*   ei  = (const int*)d_in[1];
    const int*   sel = (const int*)d_in[2];
    const int*   src = ei;
    const int*   dst = ei + EDGES;
    const float* cw1[3] = {(const float*)d_in[4],  (const float*)d_in[8],  (const float*)d_in[12]};
    const float* cb1[3] = {(const float*)d_in[5],  (const float*)d_in[9],  (const float*)d_in[13]};
    const float* cw2[3] = {(const float*)d_in[6],  (const float*)d_in[10], (const float*)d_in[14]};
    const float* cb2[3] = {(const float*)d_in[7],  (const float*)d_in[11], (const float*)d_in[15]};
    const float* fw1 = (const float*)d_in[16];
    const float* fb1 = (const float*)d_in[17];
    const float* fw2 = (const float*)d_in[18];
    const float* fb2 = (const float*)d_in[19];
    float* out = (float*)d_out;

    const size_t MB = 1024 * 1024;
    char* p = (char*)d_ws;
    unsigned int* keys = (unsigned int*)p;                   // 32 MB
    short* U    = (short*)(p + 32 * MB);                     // 16 MB (fp16)
    short* V    = (short*)(p + 48 * MB);                     // 16 MB (fp16)
    short* hb   = (short*)(p + 64 * MB);                     // 16 MB (bf16)
    short* WdT  = (short*)(p + 80 * MB);                     // 0.5 MB each
    short* w1bT = WdT + 512 * 512;
    short* W2T  = w1bT + 512 * 512;                          // fp16
    short* fw1T = W2T + 512 * 512;
    short* fw2T = fw1T + 512 * 512;
    int*   dstS = (int*)(p + 83 * MB);                       // 1 MB
    int*   srcS = (int*)(p + 84 * MB);                       // 1 MB
    int*   hist = (int*)(p + 85 * MB);                       // 64 KB
    int*   curs = hist + N_NODES;                            // 64 KB
    short* hgb  = (short*)(p + 86 * MB);                     // 4 MB
    short* t1b  = (short*)(p + 90 * MB);                     // 4 MB

    // --- sort edges by dst (edges constant across layers) ---
    (void)hipMemsetAsync(hist, 0, N_NODES * sizeof(int), stream);
    hist_kernel<<<EDGES / 256, 256, 0, stream>>>(dst, hist);
    scan_kernel<<<1, 256, 0, stream>>>(hist, curs);
    scatter_kernel<<<EDGES / 256, 256, 0, stream>>>(dst, src, curs, dstS, srcS);

    cvt_bf16_kernel<<<8192, 256, 0, stream>>>(x, hb);
    tr_kernel<<<dim3(16, 16, 2), dim3(32, 8), 0, stream>>>(fw1, fw2, fw1T, fw2T);
    (void)hipMemsetAsync(keys, 0, 32 * MB, stream);          // layer-0 key init

    for (int l = 0; l < 3; ++l) {
        prep_weights_kernel<<<dim3(16, 16, 3), dim3(32, 8), 0, stream>>>(
            cw1[l], cw2[l], WdT, w1bT, W2T);
        node_gemm_uv_kernel<<<dim3(128, 8), 256, 0, stream>>>(hb, WdT, w1bT, cb1[l], U, V);
        edge_mfma_kernel<<<4096, 256, 0, stream>>>(U, V, W2T, srcS, dstS, keys);
        decode_kernel<<<(N_NODES * HDIM) / 256, 256, 0, stream>>>(keys, cb2[l], hb);
    }

    gather_bf16_kernel<<<(4096 * 64) / 256, 256, 0, stream>>>(hb, sel, hgb);
    ffn_gemm_kernel<<<dim3(32, 4), 256, 0, stream>>>(hgb, fw1T, fb1, t1b, nullptr, 1);
    ffn_gemm_kernel<<<dim3(32, 4), 256, 0, stream>>>(t1b, fw2T, fb2, nullptr, out, 0);
}